// Round 11
// baseline (248.129 us; speedup 1.0000x reference)
//
#include <hip/hip_runtime.h>
#include <hip/hip_bf16.h>

// Problem constants (from reference)
#define V 50000
#define D 128
#define B 2048
#define P 20

// Stage-1: x[B][D] = inputs[B][V] @ W_emb[D][V]^T, split-K, A-panel-resident
#define BM 64
#define KC 896                  // 14 uniform steps of 64 k per split
#define NSTEP 14
#define NSPLIT 56               // 8 XCDs x 7 rounds
#define VPAD (NSPLIT * KC)      // 50176
#define NSLICE (VPAD / 32)      // 1568
#define NMT (B / BM)            // 32  -> grid 1792 = 7 rounds of 256

typedef float  f32x4  __attribute__((ext_vector_type(4)));
typedef short  bf16x8 __attribute__((ext_vector_type(8)));
typedef unsigned int uint4v __attribute__((ext_vector_type(4)));
typedef unsigned int uint2v __attribute__((ext_vector_type(2)));

// truncating fp32->bf16 pack of two floats into one u32 (low = a, high = b)
__device__ __forceinline__ unsigned int pk2(float a, float b) {
    return (__float_as_uint(b) & 0xFFFF0000u) | (__float_as_uint(a) >> 16);
}
// RNE fp32->bf16
__device__ __forceinline__ unsigned short f2bf(float f) {
    unsigned int u = __float_as_uint(f);
    return (unsigned short)((u + 0x7FFFu + ((u >> 16) & 1u)) >> 16);
}
__device__ __forceinline__ bf16x8 pack8(f32x4 lo, f32x4 hi) {
    union { uint4v u; bf16x8 h; } r;
    r.u.x = pk2(lo[0], lo[1]); r.u.y = pk2(lo[2], lo[3]);
    r.u.z = pk2(hi[0], hi[1]); r.u.w = pk2(hi[2], hi[3]);
    return r.h;
}

// ---- pre-pass: W_emb fp32 [D][V] -> WTF, MFMA-fragment-ordered bf16 (zero-pad to VPAD).
// WTF: slice ks5 (32 k), coltile n (16 cols), lane l: off = ks5*8192 + n*1024 + l*16.
__global__ __launch_bounds__(256)
void w2v_wcast(const float* __restrict__ Wemb, unsigned short* __restrict__ WTF) {
    __shared__ unsigned short L[128 * 128];        // 32 KB [d][128 k] swizzled chunks
    const int bk = blockIdx.x;                     // 0..391: k-window [bk*128, +128)
    const int t  = threadIdx.x;
    const int d = t >> 1, h = t & 1;
    const float* src = Wemb + (size_t)d * V + bk * 128 + h * 64;
#pragma unroll
    for (int j = 0; j < 8; ++j) {
        const int kg = bk * 128 + h * 64 + j * 8;
        f32x4 v0 = {0,0,0,0}, v1 = {0,0,0,0};
        if (kg + 8 <= V) {                         // V%8==0 -> full or pad
            const f32x4* p = reinterpret_cast<const f32x4*>(src + j * 8);
            v0 = p[0]; v1 = p[1];
        }
        uint4v u;
        u.x = pk2(v0[0], v0[1]); u.y = pk2(v0[2], v0[3]);
        u.z = pk2(v1[0], v1[1]); u.w = pk2(v1[2], v1[3]);
        const int c8 = h * 8 + j;
        *reinterpret_cast<uint4v*>((char*)L + d * 256 + ((c8 ^ (d & 15)) << 4)) = u;
    }
    __syncthreads();
    const int w = t >> 6, l = t & 63;
    const int kg4 = l >> 4, fr = l & 15;
#pragma unroll
    for (int sl = 0; sl < 4; ++sl)
#pragma unroll
        for (int j2 = 0; j2 < 2; ++j2) {
            const int n  = w + j2 * 4;
            const int dd = n * 16 + fr;
            const int c8 = sl * 4 + kg4;
            uint4v u = *reinterpret_cast<const uint4v*>(
                (char*)L + dd * 256 + ((c8 ^ (dd & 15)) << 4));
            *reinterpret_cast<uint4v*>(
                (char*)WTF + ((size_t)(bk * 4 + sl) * 8 + n) * 1024 + l * 16) = u;
        }
}

// ---- stage 1: A-panel-resident split-K GEMM ----
// Prologue: 64x896 A rows loaded as contiguous 448-B spans/thread into 112 KB LDS
// (14 swizzled [64][64] bf16 tiles). Compute: 14 uniform steps, ZERO barriers —
// W fragments register-double-buffered straight from WTF (1-KB coalesced, L1/L2-hot).
template<int FAST>
__global__ __launch_bounds__(512, 2)
void w2v_gemm(const float* __restrict__ Ain, const void* __restrict__ Wsrc,
              void* __restrict__ part) {
    __shared__ char smem[NSTEP * 8192];    // 114688 B A-panel; epilogue reuses as C-tile

    const int i   = blockIdx.x;            // 0..1791
    const int xcd = i & 7;
    const int j   = i >> 3;                // 0..223
    const int s   = xcd * 7 + (j >> 5);    // 0..55; round r => split xcd*7+r (co-resident)
    const int mt  = j & 31;
    const int m0  = mt * BM;
    const int k0  = s * KC;
    const int kend = (k0 + KC < V) ? (k0 + KC) : V;

    const int tid  = threadIdx.x;
    const int lane = tid & 63;
    const int wid  = tid >> 6;
    const int rg   = wid & 3;              // row-group: rows [rg*16, +16)
    const int wc   = wid >> 2;             // col half: cols [wc*64, +64)
    const int fr   = lane & 15;
    const int kg4  = lane >> 4;

    // ---- prologue: A panel, 8 threads/row, 448-B contiguous span each ----
    {
        const int row = tid >> 3;
        const int q   = tid & 7;
        const float* src = Ain + (size_t)(m0 + row) * V + k0 + q * 112;
        char* wbase = smem + row * 128;
#pragma unroll
        for (int jj = 0; jj < 28; ++jj) {
            const int f0 = q * 112 + jj * 4;
            f32x4 v = {0.f, 0.f, 0.f, 0.f};
            if (k0 + f0 + 4 <= kend)       // 4-granular; zero-fill tail (V%4==0)
                v = *reinterpret_cast<const f32x4*>(src + jj * 4);
            uint2v u; u.x = pk2(v[0], v[1]); u.y = pk2(v[2], v[3]);
            const int tt = f0 >> 6, c8 = (f0 >> 3) & 7, hf = (f0 >> 2) & 1;
            *reinterpret_cast<uint2v*>(wbase + tt * 8192 + ((c8 ^ (row & 7)) << 4) + hf * 8) = u;
        }
    }
    __syncthreads();

    f32x4 acc[4] = {};                     // 16x64 per wave: 4 n-frags
    const unsigned short* WT = (const unsigned short*)Wsrc;  // FAST: WTF
    const float*          Wf = (const float*)Wsrc;           // !FAST: fp32 [D][V]

    bf16x8 wfA[8], wfB[8];
    auto loadW = [&](bf16x8* wf, int t) {
        if (FAST) {
            const size_t ks5 = (size_t)s * 28 + t * 2;
#pragma unroll
            for (int u = 0; u < 2; ++u)
#pragma unroll
                for (int n = 0; n < 4; ++n)
                    wf[u * 4 + n] = *reinterpret_cast<const bf16x8*>(
                        (const char*)WT + (ks5 + u) * 8192 + (wc * 4 + n) * 1024 + lane * 16);
        } else {
#pragma unroll
            for (int u = 0; u < 2; ++u)
#pragma unroll
                for (int n = 0; n < 4; ++n) {
                    const int kg = k0 + t * 64 + u * 32 + kg4 * 8;
                    const int dd = wc * 64 + n * 16 + fr;
                    f32x4 lo = {0,0,0,0}, hi = {0,0,0,0};
                    if (kg + 8 <= V) {
                        const f32x4* p = reinterpret_cast<const f32x4*>(Wf + (size_t)dd * V + kg);
                        lo = p[0]; hi = p[1];
                    }
                    wf[u * 4 + n] = pack8(lo, hi);
                }
        }
    };
    auto computeStep = [&](const bf16x8* wf, int t) {
#pragma unroll
        for (int u = 0; u < 2; ++u) {
            const int r = rg * 16 + fr;
            const bf16x8 af = *reinterpret_cast<const bf16x8*>(
                smem + t * 8192 + r * 128 + (((u * 4 + kg4) ^ (r & 7)) << 4));
#pragma unroll
            for (int n = 0; n < 4; ++n)
                acc[n] = __builtin_amdgcn_mfma_f32_16x16x32_bf16(af, wf[u * 4 + n], acc[n], 0, 0, 0);
        }
    };

    loadW(wfA, 0);
#pragma unroll
    for (int t = 0; t < NSTEP; t += 2) {   // static 2-step ping-pong (rule #20)
        loadW(wfB, t + 1);
        computeStep(wfA, t);
        if (t + 2 < NSTEP) loadW(wfA, t + 2);
        computeStep(wfB, t + 1);
    }

    __syncthreads();                       // all panel reads done before C-tile overwrite

    // ---- epilogue (C/D layout: col = lane&15, row = kg4*4 + jj) ----
    if (!FAST) {
        float* outp = (float*)part;        // fp32 [B][D] atomic accumulate
#pragma unroll
        for (int n = 0; n < 4; ++n) {
            const int c = wc * 64 + n * 16 + fr;
#pragma unroll
            for (int jj = 0; jj < 4; ++jj)
                atomicAdd(&outp[(size_t)(m0 + rg * 16 + kg4 * 4 + jj) * D + c], acc[n][jj]);
        }
        return;
    }
    unsigned short* Cs = (unsigned short*)smem;   // [64][128] bf16 = 16 KB
#pragma unroll
    for (int n = 0; n < 4; ++n) {
        const int c = wc * 64 + n * 16 + fr;
#pragma unroll
        for (int jj = 0; jj < 4; ++jj)
            Cs[(rg * 16 + kg4 * 4 + jj) * 128 + c] = f2bf(acc[n][jj]);
    }
    __syncthreads();
    char* dstb = (char*)part + ((size_t)s * B + m0) * (D * 2);   // [s][b][d] bf16
#pragma unroll
    for (int it = 0; it < 2; ++it) {
        const int off = (it * 512 + tid) * 16;                   // 16 KB coalesced
        *reinterpret_cast<uint4v*>(dstb + off) =
            *reinterpret_cast<const uint4v*>(smem + off);
    }
}

// ---- stage 2: reduce splits + gathered cls dots + BCE + mean ----
__global__ __launch_bounds__(256)
void w2v_loss(const void* __restrict__ part, int part_bf16,
              const float* __restrict__ Wcls, const int* __restrict__ pathIdx,
              const float* __restrict__ codes, const float* __restrict__ mask,
              float* __restrict__ out) {
    const int lane = threadIdx.x & 63;
    const int wid  = threadIdx.x >> 6;
    const int b    = blockIdx.x * 4 + wid;     // one wave per sample

    float x0 = 0.f, x1 = 0.f;                  // x[b][2*lane], x[b][2*lane+1]
    if (part_bf16) {
        const unsigned* pb = (const unsigned*)part;   // 64 u32 per [s][b] row
#pragma unroll 8
        for (int s = 0; s < NSPLIT; ++s) {
            unsigned u = pb[((size_t)s * B + b) * 64 + lane];
            x0 += __uint_as_float(u << 16);
            x1 += __uint_as_float(u & 0xFFFF0000u);
        }
    } else {
        const float* pf = (const float*)part;         // [B][D] fp32, pre-reduced
        const float2 v = *reinterpret_cast<const float2*>(&pf[(size_t)b * D + lane * 2]);
        x0 = v.x; x1 = v.y;
    }

    float lsum = 0.f, msum = 0.f;
#pragma unroll
    for (int p = 0; p < P; ++p) {
        int node = pathIdx[b * P + p];
        const float2 w = *reinterpret_cast<const float2*>(&Wcls[(size_t)node * D + lane * 2]);
        float d = x0 * w.x + x1 * w.y;
#pragma unroll
        for (int off = 1; off < 64; off <<= 1)
            d += __shfl_xor(d, off, 64);
        float t  = codes[b * P + p];
        float mm = mask[b * P + p];
        float loss = fmaxf(d, 0.f) - d * t + log1pf(__expf(-fabsf(d)));
        lsum += loss * mm;
        msum += mm;
    }
    float per = (msum > 0.f) ? (lsum / msum) : 0.f;

    __shared__ float wsum[4];
    if (lane == 0) wsum[wid] = per;
    __syncthreads();
    if (threadIdx.x == 0) {
        float ssum = wsum[0] + wsum[1] + wsum[2] + wsum[3];
        atomicAdd(out, ssum * (1.0f / (float)B));
    }
}

extern "C" void kernel_launch(void* const* d_in, const int* in_sizes, int n_in,
                              void* d_out, int out_size, void* d_ws, size_t ws_size,
                              hipStream_t stream) {
    const float* inputs = (const float*)d_in[0];   // [B,V]
    const float* W_emb  = (const float*)d_in[1];   // [D,V]
    const float* W_cls  = (const float*)d_in[2];   // [V,D]
    const int*   path   = (const int*)  d_in[3];   // [B,P]
    const float* codes  = (const float*)d_in[4];   // [B,P]
    const float* mask   = (const float*)d_in[5];   // [B,P]
    float* out = (float*)d_out;

    hipMemsetAsync(d_out, 0, sizeof(float), stream);

    const size_t wtf_bytes = (size_t)NSLICE * 8192;                   // ~12.85 MB
    const size_t part_off  = (wtf_bytes + 255) & ~(size_t)255;
    const size_t part_need = part_off + (size_t)NSPLIT * B * D * 2;   // ~42.2 MB

    if (ws_size >= part_need) {
        unsigned short* WTF = (unsigned short*)d_ws;
        char* partp = (char*)d_ws + part_off;
        w2v_wcast<<<dim3(VPAD / 128), dim3(256), 0, stream>>>(W_emb, WTF);
        w2v_gemm<1><<<dim3(NMT * NSPLIT), dim3(512), 0, stream>>>(inputs, WTF, partp);
        w2v_loss<<<dim3(B / 4), dim3(256), 0, stream>>>(partp, 1, W_cls, path, codes, mask, out);
    } else {
        hipMemsetAsync(d_ws, 0, (size_t)B * D * sizeof(float), stream);
        w2v_gemm<0><<<dim3(NMT * NSPLIT), dim3(512), 0, stream>>>(inputs, W_emb, d_ws);
        w2v_loss<<<dim3(B / 4), dim3(256), 0, stream>>>(d_ws, 0, W_cls, path, codes, mask, out);
    }
}

// Round 12
// 204.366 us; speedup vs baseline: 1.2141x; 1.2141x over previous
//
#include <hip/hip_runtime.h>
#include <hip/hip_bf16.h>

// Problem constants (from reference)
#define V 50000
#define D 128
#define B 2048
#define P 20

// Stage-1: x[B][D] = inputs[B][V] @ W_emb[D][V]^T, split-K
#define BM 128
#define NSPLIT 48               // 8 XCDs x 6 splits; grid 16*48 = 768 = exactly 3 blocks/CU
#define KC 1056                 // 17 steps of 64 k (last half); split 47: 368 k = 6 steps
#define VPAD (NSPLIT * KC)      // 50688
#define NSLICE (VPAD / 32)      // 1584
#define NMT (B / BM)            // 16

typedef float  f32x4  __attribute__((ext_vector_type(4)));
typedef short  bf16x8 __attribute__((ext_vector_type(8)));
typedef unsigned int uint4v __attribute__((ext_vector_type(4)));

// truncating fp32->bf16 pack of two floats into one u32 (low = a, high = b)
__device__ __forceinline__ unsigned int pk2(float a, float b) {
    return (__float_as_uint(b) & 0xFFFF0000u) | (__float_as_uint(a) >> 16);
}
// RNE fp32->bf16
__device__ __forceinline__ unsigned short f2bf(float f) {
    unsigned int u = __float_as_uint(f);
    return (unsigned short)((u + 0x7FFFu + ((u >> 16) & 1u)) >> 16);
}
__device__ __forceinline__ bf16x8 pack8(f32x4 lo, f32x4 hi) {
    union { uint4v u; bf16x8 h; } r;
    r.u.x = pk2(lo[0], lo[1]); r.u.y = pk2(lo[2], lo[3]);
    r.u.z = pk2(hi[0], hi[1]); r.u.w = pk2(hi[2], hi[3]);
    return r.h;
}

// ---- pre-pass: W_emb fp32 [D][V] -> WTF, MFMA-fragment-ordered bf16 (zero-pad to VPAD).
// WTF: slice ks5 (32 k), coltile n (16 cols), lane l: off = ks5*8192 + n*1024 + l*16.
__global__ __launch_bounds__(256)
void w2v_wcast(const float* __restrict__ Wemb, unsigned short* __restrict__ WTF) {
    __shared__ unsigned short L[128 * 128];        // 32 KB [d][128 k] swizzled chunks
    const int bk = blockIdx.x;                     // 0..395: k-window [bk*128, +128)
    const int t  = threadIdx.x;
    const int d = t >> 1, h = t & 1;
    const float* src = Wemb + (size_t)d * V + bk * 128 + h * 64;
#pragma unroll
    for (int j = 0; j < 8; ++j) {
        const int kg = bk * 128 + h * 64 + j * 8;
        f32x4 v0 = {0,0,0,0}, v1 = {0,0,0,0};
        if (kg + 8 <= V) {                         // V%8==0 -> full or pad
            const f32x4* p = reinterpret_cast<const f32x4*>(src + j * 8);
            v0 = p[0]; v1 = p[1];
        }
        uint4v u;
        u.x = pk2(v0[0], v0[1]); u.y = pk2(v0[2], v0[3]);
        u.z = pk2(v1[0], v1[1]); u.w = pk2(v1[2], v1[3]);
        const int c8 = h * 8 + j;
        *reinterpret_cast<uint4v*>((char*)L + d * 256 + ((c8 ^ (d & 15)) << 4)) = u;
    }
    __syncthreads();
    const int w = t >> 6, l = t & 63;
    const int kg4 = l >> 4, fr = l & 15;
#pragma unroll
    for (int sl = 0; sl < 4; ++sl)
#pragma unroll
        for (int j2 = 0; j2 < 2; ++j2) {
            const int n  = w + j2 * 4;
            const int dd = n * 16 + fr;
            const int c8 = sl * 4 + kg4;
            uint4v u = *reinterpret_cast<const uint4v*>(
                (char*)L + dd * 256 + ((c8 ^ (dd & 15)) << 4));
            *reinterpret_cast<uint4v*>(
                (char*)WTF + ((size_t)(bk * 4 + sl) * 8 + n) * 1024 + l * 16) = u;
        }
}

// ---- stage 1: wave-private ZERO-BARRIER split-K GEMM ----
// Each wave owns 32 rows; private 8 KB LDS (2 bufs x 4 KB), fragment-major (no bank
// conflicts: writes = 4x256B runs, reads = contiguous 1 KB). W frags to registers from
// L2-hot WTF. No __syncthreads in the loop -> waves keep 8 KB A-prefetch in flight
// continuously (the barrier-convoy duty-cycle collapse is the diagnosed plateau cause).
template<int FAST>
__global__ __launch_bounds__(256, 3)
void w2v_gemm(const float* __restrict__ Ain, const void* __restrict__ Wsrc,
              void* __restrict__ part) {
    __shared__ char smem[32768];           // 4 waves x (2 bufs x 4 KB); epilogue C-tile

    const int i   = blockIdx.x;            // 0..767
    const int xcd = i & 7;
    const int q   = i >> 3;                // 0..95
    const int s   = xcd * 6 + (q >> 4);    // 0..47 (6 splits/XCD, all co-resident)
    const int mt  = q & 15;
    const int m0  = mt * BM;
    const int k0  = s * KC;
    const int kend = (k0 + KC < V) ? (k0 + KC) : V;
    const int nst  = (kend - k0 + 63) >> 6;        // 17 (s=47: 6)

    const int tid  = threadIdx.x;
    const int lane = tid & 63;
    const int wid  = tid >> 6;
    const int w32  = wid * 32;             // wave owns output rows [w32, w32+32)
    const int fr   = lane & 15;
    const int kg4  = lane >> 4;

    f32x4 acc[2][8] = {};

    // wave-private A staging: lane -> row w32+(l>>1), float-range [h*32, +32)
    const int arow = w32 + (lane >> 1);
    const int ah   = lane & 1;
    const float* aSrc = Ain + (size_t)(m0 + arow) * V + ah * 32;
    char* myLDS = smem + wid * 8192;
    // frag-major write base: buf*4096 + u(=ah)*2048 + mi*1024 + fr*16  (+ kg4*256)
    char* wBase = myLDS + ah * 2048 + (lane >> 5) * 1024 + ((lane >> 1) & 15) * 16;

    const unsigned short* WT = (const unsigned short*)Wsrc;  // FAST: WTF
    const float*          Wf = (const float*)Wsrc;           // !FAST: fp32 [D][V]

    f32x4 aR[8];
    auto loadA = [&](int ks) {             // 8 x f32x4, 256 B/row coverage per wave
#pragma unroll
        for (int j = 0; j < 8; ++j) {
            f32x4 v = {0.f, 0.f, 0.f, 0.f};
            if (ks + ah * 32 + j * 4 + 4 <= kend)  // 4-granular; zero tail
                v = *reinterpret_cast<const f32x4*>(aSrc + ks + j * 4);
            aR[j] = v;
        }
    };
    auto writeA = [&](int buf) {           // 4 x ds_write_b128, conflict-minimal
        char* base = wBase + buf * 4096;
#pragma unroll
        for (int j2 = 0; j2 < 4; ++j2) {   // j2 = kg4 of the piece
            uint4v u;
            u.x = pk2(aR[j2*2][0], aR[j2*2][1]);
            u.y = pk2(aR[j2*2][2], aR[j2*2][3]);
            u.z = pk2(aR[j2*2+1][0], aR[j2*2+1][1]);
            u.w = pk2(aR[j2*2+1][2], aR[j2*2+1][3]);
            *reinterpret_cast<uint4v*>(base + j2 * 256) = u;
        }
    };
    bf16x8 wf[8];
    auto loadWu = [&](int t, int u) {
        if (FAST) {                        // contiguous 1 KB per wave-instr, L2-hot
            const size_t ks5 = (size_t)(k0 + t * 64 + u * 32) >> 5;
            const char* wb = (const char*)WT + ks5 * 8192 + lane * 16;
#pragma unroll
            for (int n = 0; n < 8; ++n)
                wf[n] = *reinterpret_cast<const bf16x8*>(wb + n * 1024);
        } else {
            const int kg = k0 + t * 64 + u * 32 + kg4 * 8;
#pragma unroll
            for (int n = 0; n < 8; ++n) {
                f32x4 lo = {0,0,0,0}, hi = {0,0,0,0};
                if (kg + 8 <= V) {
                    const f32x4* p = reinterpret_cast<const f32x4*>(
                        Wf + (size_t)(n * 16 + fr) * V + kg);
                    lo = p[0]; hi = p[1];
                }
                wf[n] = pack8(lo, hi);
            }
        }
    };

    int cur = 0;
    loadA(k0);
    for (int t = 0; t < nst; ++t) {
        writeA(cur);                       // waits A(t) (only outstanding VMEM here)
        loadWu(t, 0);                      // wf(u0) issued BEFORE A(t+1)
        if (t + 1 < nst) loadA(k0 + (t + 1) * 64);   // 8 loads, stay in flight
        // ---- u = 0: consume wf (vmcnt leaves A(t+1) airborne) ----
        {
            const bf16x8 af0 = *reinterpret_cast<const bf16x8*>(myLDS + cur*4096 + lane*16);
            const bf16x8 af1 = *reinterpret_cast<const bf16x8*>(myLDS + cur*4096 + 1024 + lane*16);
#pragma unroll
            for (int n = 0; n < 8; ++n) {
                acc[0][n] = __builtin_amdgcn_mfma_f32_16x16x32_bf16(af0, wf[n], acc[0][n], 0, 0, 0);
                acc[1][n] = __builtin_amdgcn_mfma_f32_16x16x32_bf16(af1, wf[n], acc[1][n], 0, 0, 0);
            }
        }
        // ---- u = 1 ----
        loadWu(t, 1);
        {
            const bf16x8 af0 = *reinterpret_cast<const bf16x8*>(myLDS + cur*4096 + 2048 + lane*16);
            const bf16x8 af1 = *reinterpret_cast<const bf16x8*>(myLDS + cur*4096 + 3072 + lane*16);
#pragma unroll
            for (int n = 0; n < 8; ++n) {
                acc[0][n] = __builtin_amdgcn_mfma_f32_16x16x32_bf16(af0, wf[n], acc[0][n], 0, 0, 0);
                acc[1][n] = __builtin_amdgcn_mfma_f32_16x16x32_bf16(af1, wf[n], acc[1][n], 0, 0, 0);
            }
        }
        cur ^= 1;
    }

    // ---- epilogue (C/D layout: col = lane&15, row = kg4*4 + jj) ----
    if (!FAST) {
        float* outp = (float*)part;        // fp32 [B][D] atomic accumulate
#pragma unroll
        for (int m = 0; m < 2; ++m) {
            const int r0 = m0 + w32 + m * 16 + kg4 * 4;
#pragma unroll
            for (int n = 0; n < 8; ++n) {
                const int c = n * 16 + fr;
#pragma unroll
                for (int jj = 0; jj < 4; ++jj)
                    atomicAdd(&outp[(size_t)(r0 + jj) * D + c], acc[m][n][jj]);
            }
        }
        return;
    }
    // C tile: rows [w32,w32+32) x 128 cols bf16 = this wave's private 8 KB region
    unsigned short* Cs = (unsigned short*)smem;   // [128][128] bf16 = 32 KB
#pragma unroll
    for (int m = 0; m < 2; ++m) {
        const int r0 = w32 + m * 16 + kg4 * 4;
#pragma unroll
        for (int n = 0; n < 8; ++n) {
            const int c = n * 16 + fr;
#pragma unroll
            for (int jj = 0; jj < 4; ++jj)
                Cs[(r0 + jj) * 128 + c] = f2bf(acc[m][n][jj]);
        }
    }
    __syncthreads();                       // the ONLY block-wide barrier
    char* dstb = (char*)part + ((size_t)s * B + m0) * (D * 2);   // [s][b][d] bf16
#pragma unroll
    for (int it = 0; it < 8; ++it) {
        const int off = (it * 256 + tid) * 16;                   // 32 KB coalesced
        uint4v v = *reinterpret_cast<const uint4v*>((char*)smem + off);
        *reinterpret_cast<uint4v*>(dstb + off) = v;
    }
}

// ---- stage 2: reduce splits + gathered cls dots + BCE + mean ----
__global__ __launch_bounds__(256)
void w2v_loss(const void* __restrict__ part, int part_bf16,
              const float* __restrict__ Wcls, const int* __restrict__ pathIdx,
              const float* __restrict__ codes, const float* __restrict__ mask,
              float* __restrict__ out) {
    const int lane = threadIdx.x & 63;
    const int wid  = threadIdx.x >> 6;
    const int b    = blockIdx.x * 4 + wid;     // one wave per sample

    float x0 = 0.f, x1 = 0.f;                  // x[b][2*lane], x[b][2*lane+1]
    if (part_bf16) {
        const unsigned* pb = (const unsigned*)part;   // 64 u32 per [s][b] row
#pragma unroll 8
        for (int s = 0; s < NSPLIT; ++s) {
            unsigned u = pb[((size_t)s * B + b) * 64 + lane];
            x0 += __uint_as_float(u << 16);
            x1 += __uint_as_float(u & 0xFFFF0000u);
        }
    } else {
        const float* pf = (const float*)part;         // [B][D] fp32, pre-reduced
        const float2 v = *reinterpret_cast<const float2*>(&pf[(size_t)b * D + lane * 2]);
        x0 = v.x; x1 = v.y;
    }

    float lsum = 0.f, msum = 0.f;
#pragma unroll
    for (int p = 0; p < P; ++p) {
        int node = pathIdx[b * P + p];
        const float2 w = *reinterpret_cast<const float2*>(&Wcls[(size_t)node * D + lane * 2]);
        float d = x0 * w.x + x1 * w.y;
#pragma unroll
        for (int off = 1; off < 64; off <<= 1)
            d += __shfl_xor(d, off, 64);
        float t  = codes[b * P + p];
        float mm = mask[b * P + p];
        float loss = fmaxf(d, 0.f) - d * t + log1pf(__expf(-fabsf(d)));
        lsum += loss * mm;
        msum += mm;
    }
    float per = (msum > 0.f) ? (lsum / msum) : 0.f;

    __shared__ float wsum[4];
    if (lane == 0) wsum[wid] = per;
    __syncthreads();
    if (threadIdx.x == 0) {
        float ssum = wsum[0] + wsum[1] + wsum[2] + wsum[3];
        atomicAdd(out, ssum * (1.0f / (float)B));
    }
}

extern "C" void kernel_launch(void* const* d_in, const int* in_sizes, int n_in,
                              void* d_out, int out_size, void* d_ws, size_t ws_size,
                              hipStream_t stream) {
    const float* inputs = (const float*)d_in[0];   // [B,V]
    const float* W_emb  = (const float*)d_in[1];   // [D,V]
    const float* W_cls  = (const float*)d_in[2];   // [V,D]
    const int*   path   = (const int*)  d_in[3];   // [B,P]
    const float* codes  = (const float*)d_in[4];   // [B,P]
    const float* mask   = (const float*)d_in[5];   // [B,P]
    float* out = (float*)d_out;

    hipMemsetAsync(d_out, 0, sizeof(float), stream);

    const size_t wtf_bytes = (size_t)NSLICE * 8192;                   // ~13.0 MB
    const size_t part_off  = (wtf_bytes + 255) & ~(size_t)255;
    const size_t part_need = part_off + (size_t)NSPLIT * B * D * 2;   // ~38.2 MB

    if (ws_size >= part_need) {
        unsigned short* WTF = (unsigned short*)d_ws;
        char* partp = (char*)d_ws + part_off;
        w2v_wcast<<<dim3(VPAD / 128), dim3(256), 0, stream>>>(W_emb, WTF);
        w2v_gemm<1><<<dim3(NMT * NSPLIT), dim3(256), 0, stream>>>(inputs, WTF, partp);
        w2v_loss<<<dim3(B / 4), dim3(256), 0, stream>>>(partp, 1, W_cls, path, codes, mask, out);
    } else {
        hipMemsetAsync(d_ws, 0, (size_t)B * D * sizeof(float), stream);
        w2v_gemm<0><<<dim3(NMT * NSPLIT), dim3(256), 0, stream>>>(inputs, W_emb, d_ws);
        w2v_loss<<<dim3(B / 4), dim3(256), 0, stream>>>(d_ws, 0, W_cls, path, codes, mask, out);
    }
}